// Round 1
// baseline (390.278 us; speedup 1.0000x reference)
//
#include <hip/hip_runtime.h>
#include <hip/hip_bf16.h>
#include <math.h>

#define N_TOKENS    16384
#define MODEL_DIM   2048
#define NUM_EXPERTS 64
#define TOPK        2
#define NK          (N_TOKENS * TOPK)        // 32768

// d_out layout (float32 elements)
#define OFF_TOKEN_ORDER 0
#define OFF_REVERSED    (NK)                 // 32768
#define OFF_COMBINE     (2 * NK)             // 65536
#define OFF_SPLITS      (3 * NK)             // 98304
#define OFF_PROBS       (3 * NK + NUM_EXPERTS) // 98368

#define BT 64   // tokens per block in gate kernel
#define BK 64   // k-chunk
#define LROW (NUM_EXPERTS + 1)  // padded logits row

#define SORT_BLOCKS (NK / 256)  // 128

// ---------------------------------------------------------------------------
// Kernel 1: gate GEMM (fp64 accumulate) + softmax + top-2 + combine weights
// grid: N_TOKENS/BT = 256 blocks x 256 threads
// ---------------------------------------------------------------------------
__global__ __launch_bounds__(256) void gate_kernel(
    const float* __restrict__ x,   // [N, D]
    const float* __restrict__ w,   // [E, D]
    float* __restrict__ out,
    int* __restrict__ flat_idx)    // [N*K] expert ids
{
    __shared__ float a_lds[BK * BT];            // [k][token]
    __shared__ float b_lds[BK * NUM_EXPERTS];   // [k][expert]
    __shared__ float l_lds[BT * LROW];          // logits/probs [token][65]
    __shared__ float inv_lds[BT];

    const int tid = threadIdx.x;
    const int block_t0 = blockIdx.x * BT;

    const int tx = tid & 15;   // expert group (4 experts)
    const int ty = tid >> 4;   // token group  (4 tokens)

    const int lk   = tid & 15; // float4 column for staging loads
    const int lrow = tid >> 4; // row 0..15

    double acc[4][4];
#pragma unroll
    for (int i = 0; i < 4; i++)
#pragma unroll
        for (int j = 0; j < 4; j++) acc[i][j] = 0.0;

    for (int k0 = 0; k0 < MODEL_DIM; k0 += BK) {
        // stage A tile: 64 tokens x 64 k, transposed to [k][token]
#pragma unroll
        for (int j = 0; j < 4; j++) {
            const int row = lrow + j * 16;
            const float4 v = *(const float4*)(x + (size_t)(block_t0 + row) * MODEL_DIM + k0 + lk * 4);
            a_lds[(lk * 4 + 0) * BT + row] = v.x;
            a_lds[(lk * 4 + 1) * BT + row] = v.y;
            a_lds[(lk * 4 + 2) * BT + row] = v.z;
            a_lds[(lk * 4 + 3) * BT + row] = v.w;
        }
        // stage B tile: 64 experts x 64 k, transposed to [k][expert]
#pragma unroll
        for (int j = 0; j < 4; j++) {
            const int row = lrow + j * 16;
            const float4 v = *(const float4*)(w + (size_t)row * MODEL_DIM + k0 + lk * 4);
            b_lds[(lk * 4 + 0) * NUM_EXPERTS + row] = v.x;
            b_lds[(lk * 4 + 1) * NUM_EXPERTS + row] = v.y;
            b_lds[(lk * 4 + 2) * NUM_EXPERTS + row] = v.z;
            b_lds[(lk * 4 + 3) * NUM_EXPERTS + row] = v.w;
        }
        __syncthreads();

#pragma unroll 4
        for (int k = 0; k < BK; k++) {
            const float4 av = *(const float4*)(a_lds + k * BT + ty * 4);
            const float4 bv = *(const float4*)(b_lds + k * NUM_EXPERTS + tx * 4);
            double ad[4], bd[4];
            ad[0] = av.x; ad[1] = av.y; ad[2] = av.z; ad[3] = av.w;
            bd[0] = bv.x; bd[1] = bv.y; bd[2] = bv.z; bd[3] = bv.w;
#pragma unroll
            for (int i = 0; i < 4; i++)
#pragma unroll
                for (int j = 0; j < 4; j++)
                    acc[i][j] += ad[i] * bd[j];
        }
        __syncthreads();
    }

    // logits -> LDS (fp32), padded rows
#pragma unroll
    for (int i = 0; i < 4; i++)
#pragma unroll
        for (int j = 0; j < 4; j++)
            l_lds[(ty * 4 + i) * LROW + tx * 4 + j] = (float)acc[i][j];
    __syncthreads();

    // per-token softmax + top-2 (one thread per token, wave 0)
    if (tid < BT) {
        const int t = tid;
        float* row = l_lds + t * LROW;
        float m = -INFINITY;
#pragma unroll
        for (int e = 0; e < NUM_EXPERTS; e++) m = fmaxf(m, row[e]);
        float l1 = -INFINITY, l2 = -INFINITY;
        int i1 = 0, i2 = 0;
        double s = 0.0;
        for (int e = 0; e < NUM_EXPERTS; e++) {
            const float l = row[e];
            if (l > l1) { l2 = l1; i2 = i1; l1 = l; i1 = e; }
            else if (l > l2) { l2 = l; i2 = e; }
            const float ex = expf(l - m);
            s += (double)ex;
            row[e] = ex;
        }
        const float inv = (float)(1.0 / s);
        inv_lds[t] = inv;
        const float p1 = expf(l1 - m) * inv;
        const float p2 = expf(l2 - m) * inv;
        // combine = softmax([p1, p2]) with p1 >= p2
        const float e2 = expf(p2 - p1);
        const float r = 1.0f / (1.0f + e2);
        const int gtok = block_t0 + t;
        out[OFF_COMBINE + 2 * gtok]     = r;
        out[OFF_COMBINE + 2 * gtok + 1] = e2 * r;
        flat_idx[2 * gtok]     = i1;
        flat_idx[2 * gtok + 1] = i2;
    }
    __syncthreads();

    // cooperative, coalesced probs write: 64 tokens x 64 experts
#pragma unroll
    for (int r4 = 0; r4 < 4; r4++) {
        const int f = r4 * 1024 + tid * 4;
        const int t = f >> 6;
        const int e = f & 63;
        const float inv = inv_lds[t];
        float4 v;
        v.x = l_lds[t * LROW + e + 0] * inv;
        v.y = l_lds[t * LROW + e + 1] * inv;
        v.z = l_lds[t * LROW + e + 2] * inv;
        v.w = l_lds[t * LROW + e + 3] * inv;
        *(float4*)(out + OFF_PROBS + (size_t)(block_t0 + t) * NUM_EXPERTS + e) = v;
    }
}

// ---------------------------------------------------------------------------
// Kernel 2: per-block expert histogram (128 blocks x 256 threads, 1 item/thread)
// ---------------------------------------------------------------------------
__global__ __launch_bounds__(256) void hist_kernel(
    const int* __restrict__ flat_idx, int* __restrict__ blockHist)
{
    __shared__ int h[NUM_EXPERTS];
    const int tid = threadIdx.x;
    const int b = blockIdx.x;
    if (tid < NUM_EXPERTS) h[tid] = 0;
    __syncthreads();
    const int e = flat_idx[b * 256 + tid];
    atomicAdd(&h[e], 1);
    __syncthreads();
    if (tid < NUM_EXPERTS) blockHist[b * NUM_EXPERTS + tid] = h[tid];
}

// ---------------------------------------------------------------------------
// Kernel 3: scan block histograms -> per-block/expert base offsets + splits
// 1 block x 64 threads (thread = expert)
// ---------------------------------------------------------------------------
__global__ __launch_bounds__(64) void scan_kernel(
    const int* __restrict__ blockHist, int* __restrict__ blockOff,
    float* __restrict__ out)
{
    __shared__ int tot[NUM_EXPERTS];
    __shared__ int base[NUM_EXPERTS];
    const int e = threadIdx.x;
    int run = 0;
    for (int b = 0; b < SORT_BLOCKS; b++) {
        blockOff[b * NUM_EXPERTS + e] = run;
        run += blockHist[b * NUM_EXPERTS + e];
    }
    tot[e] = run;
    __syncthreads();
    if (e == 0) {
        int s = 0;
        for (int i = 0; i < NUM_EXPERTS; i++) { base[i] = s; s += tot[i]; }
    }
    __syncthreads();
    const int be = base[e];
    for (int b = 0; b < SORT_BLOCKS; b++) blockOff[b * NUM_EXPERTS + e] += be;
    out[OFF_SPLITS + e] = (float)tot[e];
}

// ---------------------------------------------------------------------------
// Kernel 4: stable scatter (counting-sort placement), deterministic
// 128 blocks x 256 threads; 4 sequential wave-steps for intra-block stability
// ---------------------------------------------------------------------------
__global__ __launch_bounds__(256) void scatter_kernel(
    const int* __restrict__ flat_idx, const int* __restrict__ blockOff,
    float* __restrict__ out)
{
    __shared__ int cnt[NUM_EXPERTS];
    const int tid = threadIdx.x;
    const int b = blockIdx.x;
    if (tid < NUM_EXPERTS) cnt[tid] = 0;
    __syncthreads();

    const int i = b * 256 + tid;
    const int e = flat_idx[i];
    const int lane = tid & 63;
    const int w = tid >> 6;
    int pos = 0;

    for (int step = 0; step < 4; step++) {
        if (w == step) {
            int rank = 0, total = 0, leader = -1;
            for (int k = 0; k < 64; k++) {
                const int ek = __shfl(e, k);
                if (ek == e) {
                    total++;
                    if (k < lane) rank++;
                    if (leader < 0) leader = k;
                }
            }
            pos = blockOff[b * NUM_EXPERTS + e] + cnt[e] + rank;
            if (leader == lane) atomicAdd(&cnt[e], total);
        }
        __syncthreads();
    }

    out[OFF_TOKEN_ORDER + pos] = (float)(i >> 1);  // token id = i / K
    out[OFF_REVERSED + i]      = (float)pos;
}

// ---------------------------------------------------------------------------
extern "C" void kernel_launch(void* const* d_in, const int* in_sizes, int n_in,
                              void* d_out, int out_size, void* d_ws, size_t ws_size,
                              hipStream_t stream) {
    const float* x = (const float*)d_in[0];   // [16384, 2048] fp32
    const float* w = (const float*)d_in[1];   // [64, 2048] fp32
    float* out = (float*)d_out;

    int* flat_idx  = (int*)d_ws;                        // 32768 ints
    int* blockHist = flat_idx + NK;                     // 128*64
    int* blockOff  = blockHist + SORT_BLOCKS * NUM_EXPERTS;

    gate_kernel<<<N_TOKENS / BT, 256, 0, stream>>>(x, w, out, flat_idx);
    hist_kernel<<<SORT_BLOCKS, 256, 0, stream>>>(flat_idx, blockHist);
    scan_kernel<<<1, 64, 0, stream>>>(blockHist, blockOff, out);
    scatter_kernel<<<SORT_BLOCKS, 256, 0, stream>>>(flat_idx, blockOff, out);
}

// Round 2
// 292.209 us; speedup vs baseline: 1.3356x; 1.3356x over previous
//
#include <hip/hip_runtime.h>
#include <math.h>

#define N_TOKENS    16384
#define MODEL_DIM   2048
#define NUM_EXPERTS 64
#define NK          (N_TOKENS * 2)          // 32768

// d_out layout (float32 elements)
#define OFF_TOKEN_ORDER 0
#define OFF_REVERSED    (NK)                // 32768
#define OFF_COMBINE     (2 * NK)            // 65536
#define OFF_SPLITS      (3 * NK)            // 98304
#define OFF_PROBS       (3 * NK + NUM_EXPERTS)

#define BT 64            // tokens per gate block
#define BK 64            // k-tile
#define NSEG 256         // sort segments (= gate blocks), 128 slots each
#define LSTRIDE 65       // padded logits row (scalar access only)

// ---------------------------------------------------------------------------
// Kernel 1: gate GEMM (fp32 inner, fp64 per-tile fold) + softmax + top-2
//           + combine weights + per-segment expert histogram
// grid 256 x 256 threads. LDS tiles use a 16B-chunk swizzle
// (chunk' = (chunk + row/4) & 15) so both staging stores and compute reads
// hit uniform bank phases (no conflicts).
// ---------------------------------------------------------------------------
__global__ __launch_bounds__(256) void gate_kernel(
    const float* __restrict__ x,   // [N, D]
    const float* __restrict__ w,   // [E, D]
    float* __restrict__ out,
    int* __restrict__ flat_idx,    // [NK]
    int* __restrict__ segHist)     // [NSEG][64]
{
    __shared__ float a_tile[BT * 68];           // swizzled [row][64] (+slack for logits reuse)
    __shared__ float b_tile[NUM_EXPERTS * BK];  // swizzled [expert][64]
    __shared__ float inv_lds[BT];

    const int tid = threadIdx.x;
    const int t0 = blockIdx.x * BT;
    const int tx = tid & 15;        // expert group (4 experts)
    const int ty = tid >> 4;        // token group  (4 tokens)
    const int lk = tid & 15;        // staging: float4 column
    const int lrow = tid >> 4;      // staging: row 0..15

    double accd[4][4];
#pragma unroll
    for (int i = 0; i < 4; i++)
#pragma unroll
        for (int j = 0; j < 4; j++) accd[i][j] = 0.0;

    for (int k0 = 0; k0 < MODEL_DIM; k0 += BK) {
        // stage A and B tiles, swizzled chunk = (lk + row/4) & 15
#pragma unroll
        for (int j = 0; j < 4; j++) {
            const int row = lrow + j * 16;
            const int sc = ((lk + (row >> 2)) & 15) * 4;
            const float4 va = *(const float4*)(x + (size_t)(t0 + row) * MODEL_DIM + k0 + lk * 4);
            *(float4*)(a_tile + row * 64 + sc) = va;
            const float4 vb = *(const float4*)(w + (size_t)row * MODEL_DIM + k0 + lk * 4);
            *(float4*)(b_tile + row * 64 + sc) = vb;
        }
        __syncthreads();

        float accf[4][4];
#pragma unroll
        for (int i = 0; i < 4; i++)
#pragma unroll
            for (int j = 0; j < 4; j++) accf[i][j] = 0.0f;

#pragma unroll 4
        for (int k4 = 0; k4 < 16; k4++) {
            const int ca = ((k4 + ty) & 15) * 4;   // row>>2 == ty for rows ty*4+i
            const int cb = ((k4 + tx) & 15) * 4;
            float4 a[4], b[4];
#pragma unroll
            for (int i = 0; i < 4; i++) a[i] = *(const float4*)(a_tile + (ty * 4 + i) * 64 + ca);
#pragma unroll
            for (int j = 0; j < 4; j++) b[j] = *(const float4*)(b_tile + (tx * 4 + j) * 64 + cb);
#pragma unroll
            for (int i = 0; i < 4; i++)
#pragma unroll
                for (int j = 0; j < 4; j++) {
                    accf[i][j] += a[i].x * b[j].x;
                    accf[i][j] += a[i].y * b[j].y;
                    accf[i][j] += a[i].z * b[j].z;
                    accf[i][j] += a[i].w * b[j].w;
                }
        }
#pragma unroll
        for (int i = 0; i < 4; i++)
#pragma unroll
            for (int j = 0; j < 4; j++) accd[i][j] += (double)accf[i][j];
        __syncthreads();
    }

    // ---- epilogue: logits -> LDS (reuse a_tile), hist (reuse b_tile) ----
    float* l_lds = a_tile;           // stride LSTRIDE, 64*65 <= 64*68
    int* hist = (int*)b_tile;

#pragma unroll
    for (int i = 0; i < 4; i++)
#pragma unroll
        for (int j = 0; j < 4; j++)
            l_lds[(ty * 4 + i) * LSTRIDE + tx * 4 + j] = (float)accd[i][j];
    if (tid < NUM_EXPERTS) hist[tid] = 0;
    __syncthreads();

    if (tid < BT) {
        const int t = tid;
        float* row = l_lds + t * LSTRIDE;
        float m = -INFINITY;
#pragma unroll
        for (int e = 0; e < NUM_EXPERTS; e++) m = fmaxf(m, row[e]);
        float l1 = -INFINITY, l2 = -INFINITY;
        int i1 = 0, i2 = 0;
        double s = 0.0;
        for (int e = 0; e < NUM_EXPERTS; e++) {
            const float l = row[e];
            if (l > l1) { l2 = l1; i2 = i1; l1 = l; i1 = e; }
            else if (l > l2) { l2 = l; i2 = e; }
            const float ex = expf(l - m);
            s += (double)ex;
            row[e] = ex;
        }
        const float inv = (float)(1.0 / s);
        inv_lds[t] = inv;
        const float p1 = expf(l1 - m) * inv;
        const float p2 = expf(l2 - m) * inv;
        const float e2 = expf(p2 - p1);
        const float r = 1.0f / (1.0f + e2);
        const int gtok = t0 + t;
        out[OFF_COMBINE + 2 * gtok]     = r;
        out[OFF_COMBINE + 2 * gtok + 1] = e2 * r;
        flat_idx[2 * gtok]     = i1;
        flat_idx[2 * gtok + 1] = i2;
        atomicAdd(&hist[i1], 1);
        atomicAdd(&hist[i2], 1);
    }
    __syncthreads();

    if (tid < NUM_EXPERTS) segHist[blockIdx.x * NUM_EXPERTS + tid] = hist[tid];

    // cooperative coalesced probs write
#pragma unroll
    for (int r4 = 0; r4 < 4; r4++) {
        const int f = r4 * 1024 + tid * 4;
        const int t = f >> 6;
        const int e = f & 63;
        const float inv = inv_lds[t];
        float4 v;
        v.x = l_lds[t * LSTRIDE + e + 0] * inv;
        v.y = l_lds[t * LSTRIDE + e + 1] * inv;
        v.z = l_lds[t * LSTRIDE + e + 2] * inv;
        v.w = l_lds[t * LSTRIDE + e + 3] * inv;
        *(float4*)(out + OFF_PROBS + (size_t)(t0 + t) * NUM_EXPERTS + e) = v;
    }
}

// ---------------------------------------------------------------------------
// Kernel 2: scan segment hists -> per-segment/expert base offsets + splits
// 1 block x 256 threads; all 64 KB of hists staged in LDS.
// ---------------------------------------------------------------------------
__global__ __launch_bounds__(256) void scan_kernel(
    const int* __restrict__ segHist, int* __restrict__ segOff,
    float* __restrict__ out)
{
    __shared__ int h[NSEG * NUM_EXPERTS];   // 64 KB
    __shared__ int base[NUM_EXPERTS];
    const int tid = threadIdx.x;
    for (int i = tid; i < NSEG * NUM_EXPERTS; i += 256) h[i] = segHist[i];
    __syncthreads();
    if (tid < NUM_EXPERTS) {
        int run = 0;
        for (int s = 0; s < NSEG; s++) {
            const int idx = s * NUM_EXPERTS + tid;
            const int v = h[idx];
            h[idx] = run;
            run += v;
        }
        base[tid] = run;  // per-expert total (temporarily)
        out[OFF_SPLITS + tid] = (float)run;
    }
    __syncthreads();
    if (tid == 0) {
        int s = 0;
        for (int e = 0; e < NUM_EXPERTS; e++) { const int v = base[e]; base[e] = s; s += v; }
    }
    __syncthreads();
    for (int i = tid; i < NSEG * NUM_EXPERTS; i += 256) segOff[i] = h[i] + base[i & 63];
}

// ---------------------------------------------------------------------------
// Kernel 3: stable scatter via ballot-match ranks; 2 barrier steps
// 128 blocks x 256 threads (2 segments of 128 slots per block)
// ---------------------------------------------------------------------------
__global__ __launch_bounds__(256) void scatter_kernel(
    const int* __restrict__ flat_idx, const int* __restrict__ segOff,
    float* __restrict__ out)
{
    __shared__ int cnt[2 * NUM_EXPERTS];
    const int tid = threadIdx.x;
    const int i = blockIdx.x * 256 + tid;
    const int e = flat_idx[i];
    const int lane = tid & 63;
    const int wv = tid >> 6;          // 0..3
    const int segslot = wv >> 1;      // which segment within block
    const int seg = i >> 7;           // global 128-slot segment

    if (tid < 2 * NUM_EXPERTS) cnt[tid] = 0;
    __syncthreads();

    // wave-wide match mask over 6 bits of expert id
    unsigned long long match = ~0ull;
#pragma unroll
    for (int b = 0; b < 6; b++) {
        const unsigned long long m = __ballot((e >> b) & 1);
        match &= ((e >> b) & 1) ? m : ~m;
    }
    const int rank = __popcll(match & ((1ull << lane) - 1ull));

    int pos = 0;
    if ((wv & 1) == 0) {
        pos = segOff[seg * NUM_EXPERTS + e] + rank;
        if (lane == __builtin_ctzll(match))
            cnt[segslot * NUM_EXPERTS + e] = __popcll(match);
    }
    __syncthreads();
    if ((wv & 1) == 1)
        pos = segOff[seg * NUM_EXPERTS + e] + cnt[segslot * NUM_EXPERTS + e] + rank;

    out[OFF_TOKEN_ORDER + pos] = (float)(i >> 1);
    out[OFF_REVERSED + i]      = (float)pos;
}

// ---------------------------------------------------------------------------
extern "C" void kernel_launch(void* const* d_in, const int* in_sizes, int n_in,
                              void* d_out, int out_size, void* d_ws, size_t ws_size,
                              hipStream_t stream) {
    const float* x = (const float*)d_in[0];   // [16384, 2048] fp32
    const float* w = (const float*)d_in[1];   // [64, 2048] fp32
    float* out = (float*)d_out;

    int* flat_idx = (int*)d_ws;                         // 32768
    int* segHist  = flat_idx + NK;                      // 256*64
    int* segOff   = segHist + NSEG * NUM_EXPERTS;       // 256*64

    gate_kernel<<<N_TOKENS / BT, 256, 0, stream>>>(x, w, out, flat_idx, segHist);
    scan_kernel<<<1, 256, 0, stream>>>(segHist, segOff, out);
    scatter_kernel<<<NK / 256, 256, 0, stream>>>(flat_idx, segOff, out);
}

// Round 3
// 249.020 us; speedup vs baseline: 1.5673x; 1.1734x over previous
//
#include <hip/hip_runtime.h>
#include <math.h>

#define N_TOKENS    16384
#define MODEL_DIM   2048
#define NUM_EXPERTS 64
#define NK          (N_TOKENS * 2)          // 32768

// d_out layout (float32 elements)
#define OFF_TOKEN_ORDER 0
#define OFF_REVERSED    (NK)                // 32768
#define OFF_COMBINE     (2 * NK)            // 65536
#define OFF_SPLITS      (3 * NK)            // 98304
#define OFF_PROBS       (3 * NK + NUM_EXPERTS)

#define BT 64            // tokens per gate block
#define BK 64            // k-tile
#define NSEG 256         // sort segments (= token blocks), 128 slots each
#define LSTRIDE 65       // padded logits row in reduce kernel

// ---------------------------------------------------------------------------
// Kernel 1: split-K gate GEMM partials. grid (256 token-blocks, S k-splits).
// fp32 chunk accumulate per 64-k tile, fp64 fold across tiles, fp32 partial out.
// LDS tiles swizzled (chunk' = (chunk + row/4) & 15): conflict-free (round-2
// measured 9.3e4 vs 3.2e7 unswizzled).
// ---------------------------------------------------------------------------
__global__ __launch_bounds__(256) void gate_partial(
    const float* __restrict__ x,   // [N, D]
    const float* __restrict__ w,   // [E, D]
    float* __restrict__ partials,  // [256][S][64*64]
    int S, int kslice)
{
    __shared__ float a_tile[BT * 64];
    __shared__ float b_tile[NUM_EXPERTS * BK];

    const int tid = threadIdx.x;
    const int tb = blockIdx.x;
    const int sp = blockIdx.y;
    const int t0 = tb * BT;
    const int kbase = sp * kslice;
    const int tx = tid & 15;        // expert group (4 experts)
    const int ty = tid >> 4;        // token group  (4 tokens)
    const int lk = tid & 15;        // staging: float4 column
    const int lrow = tid >> 4;      // staging: row 0..15

    double accd[4][4];
#pragma unroll
    for (int i = 0; i < 4; i++)
#pragma unroll
        for (int j = 0; j < 4; j++) accd[i][j] = 0.0;

    for (int k0 = kbase; k0 < kbase + kslice; k0 += BK) {
#pragma unroll
        for (int j = 0; j < 4; j++) {
            const int row = lrow + j * 16;
            const int sc = ((lk + (row >> 2)) & 15) * 4;
            const float4 va = *(const float4*)(x + (size_t)(t0 + row) * MODEL_DIM + k0 + lk * 4);
            *(float4*)(a_tile + row * 64 + sc) = va;
            const float4 vb = *(const float4*)(w + (size_t)row * MODEL_DIM + k0 + lk * 4);
            *(float4*)(b_tile + row * 64 + sc) = vb;
        }
        __syncthreads();

        float accf[4][4];
#pragma unroll
        for (int i = 0; i < 4; i++)
#pragma unroll
            for (int j = 0; j < 4; j++) accf[i][j] = 0.0f;

#pragma unroll 4
        for (int k4 = 0; k4 < 16; k4++) {
            const int ca = ((k4 + ty) & 15) * 4;   // rows ty*4+i have row>>2 == ty
            const int cb = ((k4 + tx) & 15) * 4;
            float4 a[4], b[4];
#pragma unroll
            for (int i = 0; i < 4; i++) a[i] = *(const float4*)(a_tile + (ty * 4 + i) * 64 + ca);
#pragma unroll
            for (int j = 0; j < 4; j++) b[j] = *(const float4*)(b_tile + (tx * 4 + j) * 64 + cb);
#pragma unroll
            for (int i = 0; i < 4; i++)
#pragma unroll
                for (int j = 0; j < 4; j++) {
                    accf[i][j] += a[i].x * b[j].x;
                    accf[i][j] += a[i].y * b[j].y;
                    accf[i][j] += a[i].z * b[j].z;
                    accf[i][j] += a[i].w * b[j].w;
                }
        }
#pragma unroll
        for (int i = 0; i < 4; i++)
#pragma unroll
            for (int j = 0; j < 4; j++) accd[i][j] += (double)accf[i][j];
        __syncthreads();
    }

    float* dst = partials + ((size_t)tb * S + sp) * 4096;
#pragma unroll
    for (int i = 0; i < 4; i++) {
        float4 v;
        v.x = (float)accd[i][0]; v.y = (float)accd[i][1];
        v.z = (float)accd[i][2]; v.w = (float)accd[i][3];
        *(float4*)(dst + (ty * 4 + i) * 64 + tx * 4) = v;
    }
}

// ---------------------------------------------------------------------------
// Kernel 2: reduce split-K partials (fp64 sum) + softmax + top-2 + combine
//           + per-segment hist + probs. grid 256 blocks x 256 threads.
// ---------------------------------------------------------------------------
__global__ __launch_bounds__(256) void reduce_kernel(
    const float* __restrict__ partials,
    float* __restrict__ out,
    int* __restrict__ flat_idx,
    int* __restrict__ segHist,
    int S)
{
    __shared__ float l_lds[BT * LSTRIDE];
    __shared__ float inv_lds[BT];
    __shared__ int hist[NUM_EXPERTS];

    const int tid = threadIdx.x;
    const int tb = blockIdx.x;
    const int t0 = tb * BT;
    const float* src = partials + (size_t)tb * S * 4096;

#pragma unroll
    for (int v = 0; v < 4; v++) {
        const int q = tid + v * 256;            // float4 index 0..1023
        double a0 = 0.0, a1 = 0.0, a2 = 0.0, a3 = 0.0;
        for (int s = 0; s < S; s++) {
            const float4 p = *(const float4*)(src + (size_t)s * 4096 + q * 4);
            a0 += (double)p.x; a1 += (double)p.y; a2 += (double)p.z; a3 += (double)p.w;
        }
        const int f = q * 4;
        const int t = f >> 6;
        const int e = f & 63;
        float* row = l_lds + t * LSTRIDE + e;
        row[0] = (float)a0; row[1] = (float)a1; row[2] = (float)a2; row[3] = (float)a3;
    }
    if (tid < NUM_EXPERTS) hist[tid] = 0;
    __syncthreads();

    if (tid < BT) {
        const int t = tid;
        float* row = l_lds + t * LSTRIDE;
        float m = -INFINITY;
#pragma unroll
        for (int e = 0; e < NUM_EXPERTS; e++) m = fmaxf(m, row[e]);
        float l1 = -INFINITY, l2 = -INFINITY;
        int i1 = 0, i2 = 0;
        double s = 0.0;
        for (int e = 0; e < NUM_EXPERTS; e++) {
            const float l = row[e];
            if (l > l1) { l2 = l1; i2 = i1; l1 = l; i1 = e; }
            else if (l > l2) { l2 = l; i2 = e; }
            const float ex = expf(l - m);
            s += (double)ex;
            row[e] = ex;
        }
        const float inv = (float)(1.0 / s);
        inv_lds[t] = inv;
        const float p1 = expf(l1 - m) * inv;
        const float p2 = expf(l2 - m) * inv;
        const float e2 = expf(p2 - p1);
        const float r = 1.0f / (1.0f + e2);
        const int gtok = t0 + t;
        out[OFF_COMBINE + 2 * gtok]     = r;
        out[OFF_COMBINE + 2 * gtok + 1] = e2 * r;
        flat_idx[2 * gtok]     = i1;
        flat_idx[2 * gtok + 1] = i2;
        atomicAdd(&hist[i1], 1);
        atomicAdd(&hist[i2], 1);
    }
    __syncthreads();

    if (tid < NUM_EXPERTS) segHist[tb * NUM_EXPERTS + tid] = hist[tid];

    // coalesced probs write (also safely overwrites the S=1 in-place fallback)
#pragma unroll
    for (int r4 = 0; r4 < 4; r4++) {
        const int f = r4 * 1024 + tid * 4;
        const int t = f >> 6;
        const int e = f & 63;
        const float inv = inv_lds[t];
        float4 v;
        v.x = l_lds[t * LSTRIDE + e + 0] * inv;
        v.y = l_lds[t * LSTRIDE + e + 1] * inv;
        v.z = l_lds[t * LSTRIDE + e + 2] * inv;
        v.w = l_lds[t * LSTRIDE + e + 3] * inv;
        *(float4*)(out + OFF_PROBS + (size_t)(t0 + t) * NUM_EXPERTS + e) = v;
    }
}

// ---------------------------------------------------------------------------
// Kernel 3: scan segment hists. 2-level: 4 groups of 64 segments (chain len 64)
// + wave-shuffle prefix for expert bases. 1 block x 256 threads.
// ---------------------------------------------------------------------------
__global__ __launch_bounds__(256) void scan_kernel(
    const int* __restrict__ segHist, int* __restrict__ segOff,
    float* __restrict__ out)
{
    __shared__ int h[NSEG * NUM_EXPERTS];   // 64 KB
    __shared__ int gtot[4 * NUM_EXPERTS];
    __shared__ int base[NUM_EXPERTS];
    const int tid = threadIdx.x;
    for (int i = tid; i < NSEG * NUM_EXPERTS / 4; i += 256)
        *(int4*)(h + i * 4) = *(const int4*)(segHist + i * 4);
    __syncthreads();

    const int e = tid & 63;
    const int g = tid >> 6;                 // 0..3
    int run = 0;
    for (int s = g * 64; s < g * 64 + 64; s++) {
        const int idx = s * NUM_EXPERTS + e;
        const int v = h[idx];
        h[idx] = run;
        run += v;
    }
    gtot[g * NUM_EXPERTS + e] = run;
    __syncthreads();

    if (tid < NUM_EXPERTS) {
        int b = 0;
#pragma unroll
        for (int gg = 0; gg < 4; gg++) {
            const int t = gtot[gg * NUM_EXPERTS + tid];
            gtot[gg * NUM_EXPERTS + tid] = b;
            b += t;
        }
        out[OFF_SPLITS + tid] = (float)b;
        int xs = b;                          // inclusive wave scan over experts
#pragma unroll
        for (int off = 1; off < 64; off <<= 1) {
            const int v = __shfl_up(xs, off);
            if (tid >= off) xs += v;
        }
        base[tid] = xs - b;                  // exclusive
    }
    __syncthreads();

    const int myoff = gtot[g * NUM_EXPERTS + e] + base[e];
    for (int s = g * 64; s < g * 64 + 64; s++) {
        const int idx = s * NUM_EXPERTS + e;
        segOff[idx] = h[idx] + myoff;
    }
}

// ---------------------------------------------------------------------------
// Kernel 4: stable scatter via ballot-match ranks (unchanged, round-2 verified)
// ---------------------------------------------------------------------------
__global__ __launch_bounds__(256) void scatter_kernel(
    const int* __restrict__ flat_idx, const int* __restrict__ segOff,
    float* __restrict__ out)
{
    __shared__ int cnt[2 * NUM_EXPERTS];
    const int tid = threadIdx.x;
    const int i = blockIdx.x * 256 + tid;
    const int e = flat_idx[i];
    const int lane = tid & 63;
    const int wv = tid >> 6;
    const int segslot = wv >> 1;
    const int seg = i >> 7;

    if (tid < 2 * NUM_EXPERTS) cnt[tid] = 0;
    __syncthreads();

    unsigned long long match = ~0ull;
#pragma unroll
    for (int b = 0; b < 6; b++) {
        const unsigned long long m = __ballot((e >> b) & 1);
        match &= ((e >> b) & 1) ? m : ~m;
    }
    const int rank = __popcll(match & ((1ull << lane) - 1ull));

    int pos = 0;
    if ((wv & 1) == 0) {
        pos = segOff[seg * NUM_EXPERTS + e] + rank;
        if (lane == __builtin_ctzll(match))
            cnt[segslot * NUM_EXPERTS + e] = __popcll(match);
    }
    __syncthreads();
    if ((wv & 1) == 1)
        pos = segOff[seg * NUM_EXPERTS + e] + cnt[segslot * NUM_EXPERTS + e] + rank;

    out[OFF_TOKEN_ORDER + pos] = (float)(i >> 1);
    out[OFF_REVERSED + i]      = (float)pos;
}

// ---------------------------------------------------------------------------
extern "C" void kernel_launch(void* const* d_in, const int* in_sizes, int n_in,
                              void* d_out, int out_size, void* d_ws, size_t ws_size,
                              hipStream_t stream) {
    const float* x = (const float*)d_in[0];   // [16384, 2048] fp32
    const float* w = (const float*)d_in[1];   // [64, 2048] fp32
    float* out = (float*)d_out;

    int* flat_idx = (int*)d_ws;                          // NK ints
    int* segHist  = flat_idx + NK;                       // 256*64
    int* segOff   = segHist + NSEG * NUM_EXPERTS;        // 256*64
    float* ws_part = (float*)(segOff + NSEG * NUM_EXPERTS);

    const size_t fixed_bytes = ((size_t)NK + 2 * NSEG * NUM_EXPERTS) * 4;
    const size_t avail = ws_size > fixed_bytes ? ws_size - fixed_bytes : 0;
    const size_t part1 = (size_t)N_TOKENS * NUM_EXPERTS * 4;   // 4 MB per split

    int S;
    float* partials = ws_part;
    if      (avail >= 8 * part1) S = 8;
    else if (avail >= 4 * part1) S = 4;
    else if (avail >= 2 * part1) S = 2;
    else if (avail >= 1 * part1) S = 1;
    else { S = 1; partials = out + OFF_PROBS; }  // in-place: reduce reads then overwrites
    const int kslice = MODEL_DIM / S;

    gate_partial<<<dim3(N_TOKENS / BT, S), 256, 0, stream>>>(x, w, partials, S, kslice);
    reduce_kernel<<<NSEG, 256, 0, stream>>>(partials, out, flat_idx, segHist, S);
    scan_kernel<<<1, 256, 0, stream>>>(segHist, segOff, out);
    scatter_kernel<<<NK / 256, 256, 0, stream>>>(flat_idx, segOff, out);
}